// Round 3
// baseline (389.326 us; speedup 1.0000x reference)
//
#include <hip/hip_runtime.h>

#define VOCAB 32000
#define NROWS 4096
#define IGNORE_INDEX (-100)
#define TPB 256
#define NITEMS (VOCAB / 4)            // 8000 float4 per row
#define FULL_ITERS (NITEMS / TPB)     // 31 uniform iterations
#define TAIL_BASE (FULL_ITERS * TPB)  // 7936; tail = 64 items (threads 0..63)

typedef float f32x4 __attribute__((ext_vector_type(4)));

__device__ __forceinline__ float jsd_term(float lpv, float lqv) {
  float p = __expf(lpv);
  float q = __expf(lqv);
  float lm = __logf(0.5f * (p + q));
  return p * (lpv - lm) + q * (lqv - lm);
}

// One block per row; last finished block also does the global mean.
__global__ __launch_bounds__(TPB) void jsd_fused_kernel(
    const f32x4* __restrict__ lq4g,
    const f32x4* __restrict__ lp4g,
    const int* __restrict__ label,
    float* __restrict__ row_loss,
    unsigned int* __restrict__ counter,
    float* __restrict__ out) {
  const int row = blockIdx.x;
  const f32x4* lp4 = lp4g + (size_t)row * NITEMS;
  const f32x4* lq4 = lq4g + (size_t)row * NITEMS;

  float acc = 0.0f;
#pragma unroll 2
  for (int k = 0; k < FULL_ITERS; ++k) {
    const int i = threadIdx.x + k * TPB;
    f32x4 lp = lp4[i];
    f32x4 lq = lq4[i];
#pragma unroll
    for (int c = 0; c < 4; ++c) acc += jsd_term(lp[c], lq[c]);
  }
  if (threadIdx.x < (NITEMS - TAIL_BASE)) {
    const int i = TAIL_BASE + threadIdx.x;
    f32x4 lp = lp4[i];
    f32x4 lq = lq4[i];
#pragma unroll
    for (int c = 0; c < 4; ++c) acc += jsd_term(lp[c], lq[c]);
  }

  // wave64 shuffle reduce, then cross-wave via LDS (fixed order -> deterministic)
#pragma unroll
  for (int off = 32; off > 0; off >>= 1) acc += __shfl_down(acc, off, 64);

  __shared__ float smem[4];
  __shared__ unsigned int ticket;
  const int lane = threadIdx.x & 63;
  const int wid = threadIdx.x >> 6;
  if (lane == 0) smem[wid] = acc;
  __syncthreads();
  if (threadIdx.x == 0) {
    float total = smem[0] + smem[1] + smem[2] + smem[3];
    row_loss[row] = (label[row] != IGNORE_INDEX) ? 0.5f * total : 0.0f;
    __threadfence();                       // publish row_loss device-wide
    ticket = atomicAdd(counter, 1u);       // device-scope
  }
  __syncthreads();

  if (ticket == NROWS - 1) {
    __threadfence();                       // acquire: see all rows' results
    float sum = 0.0f;
    int cnt = 0;
    const volatile float* rl = row_loss;
    for (int i = threadIdx.x; i < NROWS; i += TPB) {
      sum += rl[i];
      cnt += (label[i] != IGNORE_INDEX) ? 1 : 0;
    }
#pragma unroll
    for (int off = 32; off > 0; off >>= 1) {
      sum += __shfl_down(sum, off, 64);
      cnt += __shfl_down(cnt, off, 64);
    }
    __shared__ float ssum[4];
    __shared__ int scnt[4];
    if (lane == 0) { ssum[wid] = sum; scnt[wid] = cnt; }
    __syncthreads();
    if (threadIdx.x == 0) {
      float total = ssum[0] + ssum[1] + ssum[2] + ssum[3];
      int n = scnt[0] + scnt[1] + scnt[2] + scnt[3];
      out[0] = (n > 0) ? total / fmaxf((float)n, 1.0f) : 0.0f;
    }
  }
}

extern "C" void kernel_launch(void* const* d_in, const int* in_sizes, int n_in,
                              void* d_out, int out_size, void* d_ws, size_t ws_size,
                              hipStream_t stream) {
  const f32x4* log_q = (const f32x4*)d_in[0];
  const f32x4* log_p = (const f32x4*)d_in[1];
  const int* label = (const int*)d_in[2];
  float* out = (float*)d_out;
  float* row_loss = (float*)d_ws;                                  // NROWS floats
  unsigned int* counter = (unsigned int*)((char*)d_ws + NROWS * sizeof(float));

  hipMemsetAsync(counter, 0, sizeof(unsigned int), stream);        // reset ticket each call
  jsd_fused_kernel<<<NROWS, TPB, 0, stream>>>(log_q, log_p, label, row_loss, counter, out);
}

// Round 4
// 191.822 us; speedup vs baseline: 2.0296x; 2.0296x over previous
//
#include <hip/hip_runtime.h>

#define VOCAB 32000
#define NROWS 4096
#define IGNORE_INDEX (-100)
#define TPB 256
#define NITEMS (VOCAB / 4)  // 8000 float4 per row

typedef float f32x4 __attribute__((ext_vector_type(4)));

__device__ __forceinline__ float jsd_term(float lpv, float lqv) {
  float p = __expf(lpv);
  float q = __expf(lqv);
  float lm = __logf(0.5f * (p + q));
  return p * (lpv - lm) + q * (lqv - lm);
}

// ---------------------------------------------------------------------------
// Kernel 1: one block per TWO adjacent rows (2048 blocks). Two independent
// accumulators double the loads in flight and halve the reduction tails.
// No fences, no atomics — deterministic fixed-order reduction.
// ---------------------------------------------------------------------------
__global__ __launch_bounds__(TPB) void jsd_rows_kernel(
    const f32x4* __restrict__ lq4g,
    const f32x4* __restrict__ lp4g,
    const int* __restrict__ label,
    float* __restrict__ row_loss) {
  const int row0 = blockIdx.x * 2;
  const f32x4* lp0 = lp4g + (size_t)row0 * NITEMS;
  const f32x4* lq0 = lq4g + (size_t)row0 * NITEMS;
  const f32x4* lp1 = lp0 + NITEMS;
  const f32x4* lq1 = lq0 + NITEMS;

  float acc0 = 0.0f, acc1 = 0.0f;
  for (int i = threadIdx.x; i < NITEMS; i += TPB) {
    f32x4 a = lp0[i];
    f32x4 b = lq0[i];
    f32x4 c = lp1[i];
    f32x4 d = lq1[i];
#pragma unroll
    for (int k = 0; k < 4; ++k) acc0 += jsd_term(a[k], b[k]);
#pragma unroll
    for (int k = 0; k < 4; ++k) acc1 += jsd_term(c[k], d[k]);
  }

  // wave64 shuffle reduce both rows, then cross-wave via LDS
#pragma unroll
  for (int off = 32; off > 0; off >>= 1) {
    acc0 += __shfl_down(acc0, off, 64);
    acc1 += __shfl_down(acc1, off, 64);
  }
  __shared__ float smem0[4];
  __shared__ float smem1[4];
  const int lane = threadIdx.x & 63;
  const int wid = threadIdx.x >> 6;
  if (lane == 0) { smem0[wid] = acc0; smem1[wid] = acc1; }
  __syncthreads();
  if (threadIdx.x == 0) {
    float t0 = smem0[0] + smem0[1] + smem0[2] + smem0[3];
    float t1 = smem1[0] + smem1[1] + smem1[2] + smem1[3];
    row_loss[row0]     = (label[row0]     != IGNORE_INDEX) ? 0.5f * t0 : 0.0f;
    row_loss[row0 + 1] = (label[row0 + 1] != IGNORE_INDEX) ? 0.5f * t1 : 0.0f;
  }
}

// ---------------------------------------------------------------------------
// Kernel 2: single block; deterministic reduce of 4096 row losses + count.
// ---------------------------------------------------------------------------
__global__ __launch_bounds__(TPB) void jsd_finalize_kernel(
    const float* __restrict__ row_loss,
    const int* __restrict__ label,
    float* __restrict__ out) {
  float sum = 0.0f;
  int cnt = 0;
  for (int i = threadIdx.x; i < NROWS; i += TPB) {
    sum += row_loss[i];
    cnt += (label[i] != IGNORE_INDEX) ? 1 : 0;
  }
#pragma unroll
  for (int off = 32; off > 0; off >>= 1) {
    sum += __shfl_down(sum, off, 64);
    cnt += __shfl_down(cnt, off, 64);
  }
  __shared__ float ssum[4];
  __shared__ int scnt[4];
  const int lane = threadIdx.x & 63;
  const int wid = threadIdx.x >> 6;
  if (lane == 0) { ssum[wid] = sum; scnt[wid] = cnt; }
  __syncthreads();
  if (threadIdx.x == 0) {
    float total = ssum[0] + ssum[1] + ssum[2] + ssum[3];
    int n = scnt[0] + scnt[1] + scnt[2] + scnt[3];
    out[0] = (n > 0) ? total / fmaxf((float)n, 1.0f) : 0.0f;
  }
}

extern "C" void kernel_launch(void* const* d_in, const int* in_sizes, int n_in,
                              void* d_out, int out_size, void* d_ws, size_t ws_size,
                              hipStream_t stream) {
  const f32x4* log_q = (const f32x4*)d_in[0];
  const f32x4* log_p = (const f32x4*)d_in[1];
  const int* label = (const int*)d_in[2];
  float* out = (float*)d_out;
  float* row_loss = (float*)d_ws;  // NROWS floats

  jsd_rows_kernel<<<NROWS / 2, TPB, 0, stream>>>(log_q, log_p, label, row_loss);
  jsd_finalize_kernel<<<1, TPB, 0, stream>>>(row_loss, label, out);
}

// Round 5
// 166.279 us; speedup vs baseline: 2.3414x; 1.1536x over previous
//
#include <hip/hip_runtime.h>

#define VOCAB 32000
#define NROWS 4096
#define IGNORE_INDEX (-100)
#define TPB 256
#define NITEMS (VOCAB / 4)  // 8000 float4 per row

typedef float f32x4 __attribute__((ext_vector_type(4)));

__device__ __forceinline__ float jsd_term(float lpv, float lqv) {
  float p = __expf(lpv);
  float q = __expf(lqv);
  float lm = __logf(0.5f * (p + q));
  return p * (lpv - lm) + q * (lqv - lm);
}

// ---------------------------------------------------------------------------
// Kernel 1: one block per TWO adjacent rows (2048 blocks). Non-temporal
// (no-allocate) loads on the zero-reuse streams. No fences, no atomics.
// ---------------------------------------------------------------------------
__global__ __launch_bounds__(TPB) void jsd_rows_kernel(
    const f32x4* __restrict__ lq4g,
    const f32x4* __restrict__ lp4g,
    const int* __restrict__ label,
    float* __restrict__ row_loss) {
  const int row0 = blockIdx.x * 2;
  const f32x4* lp0 = lp4g + (size_t)row0 * NITEMS;
  const f32x4* lq0 = lq4g + (size_t)row0 * NITEMS;
  const f32x4* lp1 = lp0 + NITEMS;
  const f32x4* lq1 = lq0 + NITEMS;

  float acc0 = 0.0f, acc1 = 0.0f;
  for (int i = threadIdx.x; i < NITEMS; i += TPB) {
    f32x4 a = __builtin_nontemporal_load(lp0 + i);
    f32x4 b = __builtin_nontemporal_load(lq0 + i);
    f32x4 c = __builtin_nontemporal_load(lp1 + i);
    f32x4 d = __builtin_nontemporal_load(lq1 + i);
#pragma unroll
    for (int k = 0; k < 4; ++k) acc0 += jsd_term(a[k], b[k]);
#pragma unroll
    for (int k = 0; k < 4; ++k) acc1 += jsd_term(c[k], d[k]);
  }

  // wave64 shuffle reduce both rows, then cross-wave via LDS
#pragma unroll
  for (int off = 32; off > 0; off >>= 1) {
    acc0 += __shfl_down(acc0, off, 64);
    acc1 += __shfl_down(acc1, off, 64);
  }
  __shared__ float smem0[4];
  __shared__ float smem1[4];
  const int lane = threadIdx.x & 63;
  const int wid = threadIdx.x >> 6;
  if (lane == 0) { smem0[wid] = acc0; smem1[wid] = acc1; }
  __syncthreads();
  if (threadIdx.x == 0) {
    float t0 = smem0[0] + smem0[1] + smem0[2] + smem0[3];
    float t1 = smem1[0] + smem1[1] + smem1[2] + smem1[3];
    row_loss[row0]     = (label[row0]     != IGNORE_INDEX) ? 0.5f * t0 : 0.0f;
    row_loss[row0 + 1] = (label[row0 + 1] != IGNORE_INDEX) ? 0.5f * t1 : 0.0f;
  }
}

// ---------------------------------------------------------------------------
// Kernel 2: single block; deterministic reduce of 4096 row losses + count.
// ---------------------------------------------------------------------------
__global__ __launch_bounds__(TPB) void jsd_finalize_kernel(
    const float* __restrict__ row_loss,
    const int* __restrict__ label,
    float* __restrict__ out) {
  float sum = 0.0f;
  int cnt = 0;
  for (int i = threadIdx.x; i < NROWS; i += TPB) {
    sum += row_loss[i];
    cnt += (label[i] != IGNORE_INDEX) ? 1 : 0;
  }
#pragma unroll
  for (int off = 32; off > 0; off >>= 1) {
    sum += __shfl_down(sum, off, 64);
    cnt += __shfl_down(cnt, off, 64);
  }
  __shared__ float ssum[4];
  __shared__ int scnt[4];
  const int lane = threadIdx.x & 63;
  const int wid = threadIdx.x >> 6;
  if (lane == 0) { ssum[wid] = sum; scnt[wid] = cnt; }
  __syncthreads();
  if (threadIdx.x == 0) {
    float total = ssum[0] + ssum[1] + ssum[2] + ssum[3];
    int n = scnt[0] + scnt[1] + scnt[2] + scnt[3];
    out[0] = (n > 0) ? total / fmaxf((float)n, 1.0f) : 0.0f;
  }
}

extern "C" void kernel_launch(void* const* d_in, const int* in_sizes, int n_in,
                              void* d_out, int out_size, void* d_ws, size_t ws_size,
                              hipStream_t stream) {
  const f32x4* log_q = (const f32x4*)d_in[0];
  const f32x4* log_p = (const f32x4*)d_in[1];
  const int* label = (const int*)d_in[2];
  float* out = (float*)d_out;
  float* row_loss = (float*)d_ws;  // NROWS floats

  jsd_rows_kernel<<<NROWS / 2, TPB, 0, stream>>>(log_q, log_p, label, row_loss);
  jsd_finalize_kernel<<<1, TPB, 0, stream>>>(row_loss, label, out);
}